// Round 1
// baseline (127.554 us; speedup 1.0000x reference)
//
#include <hip/hip_runtime.h>

// RuleNet: out[b] = 5 + sum_c rw[c] * min_j( mu[c,j]*x[b,j] + (1-mu[c,j]) )
// with x = [x0, 1-x0], mu = sigmoid(conjunctions).
// Rewrite: fit(b,c) = 1 - max_v max( mu1[c,v]*(1-x0[b,v]), mu2[c,v]*x0[b,v] ).

#define B_    1024
#define C_    512
#define V_    256
#define TWOV  512

#define CCHUNK 16              // conjunctions per block
#define NCHUNK (C_ / CCHUNK)   // 32
#define BPW    8               // batches per wave (8 vslots x 8 batches = 64 lanes)
#define BPB    32              // batches per block (4 waves)

// ---------- kernel 1: mu = sigmoid(conjunctions), vectorized float4 ----------
__global__ __launch_bounds__(256) void k_sigmoid(const float* __restrict__ conj,
                                                 float* __restrict__ mu) {
    int i = blockIdx.x * 256 + threadIdx.x;           // 65536 threads, one float4 each
    const float4* cp = reinterpret_cast<const float4*>(conj);
    float4* mp = reinterpret_cast<float4*>(mu);
    float4 z = cp[i];
    float4 r;
    r.x = 1.0f / (1.0f + expf(-z.x));
    r.y = 1.0f / (1.0f + expf(-z.y));
    r.z = 1.0f / (1.0f + expf(-z.z));
    r.w = 1.0f / (1.0f + expf(-z.w));
    mp[i] = r;
}

// ---------- kernel 2: main fuzzy-AND + weighted partial sums ----------
__global__ __launch_bounds__(256) void k_main(const float* __restrict__ x0,
                                              const float* __restrict__ mu,
                                              const float* __restrict__ rw,
                                              float* __restrict__ partial) {
    const int lane  = threadIdx.x & 63;
    const int wave  = threadIdx.x >> 6;
    const int vslot = lane & 7;     // 8 v-slots of 32 v's each
    const int bloc  = lane >> 3;    // 8 batches per wave
    const int b     = blockIdx.y * BPB + wave * BPW + bloc;
    const int c0    = blockIdx.x * CCHUNK;

    // x-row slice register-resident: v = vslot*32 + i, i in [0,32)
    float xr[32], tr[32];
    const float4* xp = reinterpret_cast<const float4*>(x0 + (size_t)b * V_ + vslot * 32);
#pragma unroll
    for (int i = 0; i < 8; ++i) {
        float4 v = xp[i];
        xr[4*i+0] = v.x;  tr[4*i+0] = 1.0f - v.x;
        xr[4*i+1] = v.y;  tr[4*i+1] = 1.0f - v.y;
        xr[4*i+2] = v.z;  tr[4*i+2] = 1.0f - v.z;
        xr[4*i+3] = v.w;  tr[4*i+3] = 1.0f - v.w;
    }

    float acc = 0.0f;
    for (int c = c0; c < c0 + CCHUNK; ++c) {
        const float4* m1 = reinterpret_cast<const float4*>(mu + (size_t)c * TWOV + vslot * 32);
        const float4* m2 = reinterpret_cast<const float4*>(mu + (size_t)c * TWOV + V_ + vslot * 32);
        // 4 independent max chains for ILP; compiler fuses fmaxf pairs into v_max3_f32
        float p0 = 0.0f, p1 = 0.0f, p2 = 0.0f, p3 = 0.0f;
#pragma unroll
        for (int i = 0; i < 8; ++i) {
            float4 a = m1[i];
            float4 q = m2[i];
            p0 = fmaxf(p0, fmaxf(a.x * tr[4*i+0], q.x * xr[4*i+0]));
            p1 = fmaxf(p1, fmaxf(a.y * tr[4*i+1], q.y * xr[4*i+1]));
            p2 = fmaxf(p2, fmaxf(a.z * tr[4*i+2], q.z * xr[4*i+2]));
            p3 = fmaxf(p3, fmaxf(a.w * tr[4*i+3], q.w * xr[4*i+3]));
        }
        float m = fmaxf(fmaxf(p0, p1), fmaxf(p2, p3));
        // reduce across the 8 v-slots (lane bits 0..2)
        m = fmaxf(m, __shfl_xor(m, 1, 64));
        m = fmaxf(m, __shfl_xor(m, 2, 64));
        m = fmaxf(m, __shfl_xor(m, 4, 64));
        acc += rw[c] * (1.0f - m);
    }
    if (vslot == 0) partial[(size_t)blockIdx.x * B_ + b] = acc;
}

// ---------- kernel 3: deterministic final reduction over c-chunks ----------
__global__ __launch_bounds__(256) void k_final(const float* __restrict__ partial,
                                               float* __restrict__ out) {
    int b = blockIdx.x * 256 + threadIdx.x;
    if (b < B_) {
        float s = 5.0f;
#pragma unroll
        for (int k = 0; k < NCHUNK; ++k) s += partial[(size_t)k * B_ + b];
        out[b] = s;
    }
}

// ---------- fallback (ws too small): naive but correct ----------
__global__ __launch_bounds__(256) void k_naive(const float* __restrict__ x0,
                                               const float* __restrict__ conj,
                                               const float* __restrict__ rw,
                                               float* __restrict__ out) {
    int b = blockIdx.x;
    int t = threadIdx.x;
    __shared__ float red[256];
    float acc = 0.0f;
    for (int c = t; c < C_; c += 256) {
        float m = 0.0f;
        for (int v = 0; v < V_; ++v) {
            float mu1 = 1.0f / (1.0f + expf(-conj[(size_t)c * TWOV + v]));
            float mu2 = 1.0f / (1.0f + expf(-conj[(size_t)c * TWOV + V_ + v]));
            float x = x0[(size_t)b * V_ + v];
            m = fmaxf(m, fmaxf(mu1 * (1.0f - x), mu2 * x));
        }
        acc += rw[c] * (1.0f - m);
    }
    red[t] = acc;
    __syncthreads();
    for (int s = 128; s > 0; s >>= 1) {
        if (t < s) red[t] += red[t + s];
        __syncthreads();
    }
    if (t == 0) out[b] = 5.0f + red[0];
}

extern "C" void kernel_launch(void* const* d_in, const int* in_sizes, int n_in,
                              void* d_out, int out_size, void* d_ws, size_t ws_size,
                              hipStream_t stream) {
    const float* x0   = (const float*)d_in[0];
    const float* conj = (const float*)d_in[1];
    const float* rw   = (const float*)d_in[2];
    float* out = (float*)d_out;

    const size_t mu_elems = (size_t)C_ * TWOV;            // 262144 floats
    const size_t part_elems = (size_t)NCHUNK * B_;        // 32768 floats
    const size_t need = (mu_elems + part_elems) * sizeof(float);

    if (ws_size < need) {
        // correctness fallback (slow) if scratch is unexpectedly small
        k_naive<<<B_, 256, 0, stream>>>(x0, conj, rw, out);
        return;
    }

    float* mu = (float*)d_ws;
    float* partial = mu + mu_elems;

    k_sigmoid<<<(C_ * TWOV) / (256 * 4), 256, 0, stream>>>(conj, mu);
    dim3 grid(NCHUNK, B_ / BPB);  // 32 x 32 blocks, 256 threads each
    k_main<<<grid, 256, 0, stream>>>(x0, mu, rw, partial);
    k_final<<<(B_ + 255) / 256, 256, 0, stream>>>(partial, out);
}

// Round 2
// 71.249 us; speedup vs baseline: 1.7903x; 1.7903x over previous
//
#include <hip/hip_runtime.h>

// RuleNet: out[b] = 5 + sum_c rw[c] * min_j( mu[c,j]*x[b,j] + (1-mu[c,j]) )
// with x = [x0, 1-x0], mu = sigmoid(conjunctions).
// Rewrite: fit(b,c) = 1 - max_v max( mu1[c,v]*(1-x0[b,v]), mu2[c,v]*x0[b,v] )
//          mu1*(1-x) = fma(-mu1, x, mu1)  -> no (1-x) array needed.

#define B_    1024
#define C_    512
#define V_    256
#define TWOV  512

#define CCHUNK 16              // conjunctions per block
#define NCHUNK (C_ / CCHUNK)   // 32
// wave layout: 16 v-slots (16 v each) x 4 batches = 64 lanes
#define BPW    4               // batches per wave
#define BPB    16              // batches per block (4 waves)

// ---------- kernel 1: mu = sigmoid(conjunctions), vectorized float4 ----------
__global__ __launch_bounds__(256) void k_sigmoid(const float* __restrict__ conj,
                                                 float* __restrict__ mu) {
    int i = blockIdx.x * 256 + threadIdx.x;           // 65536 threads, one float4 each
    const float4* cp = reinterpret_cast<const float4*>(conj);
    float4* mp = reinterpret_cast<float4*>(mu);
    float4 z = cp[i];
    float4 r;
    r.x = 1.0f / (1.0f + expf(-z.x));
    r.y = 1.0f / (1.0f + expf(-z.y));
    r.z = 1.0f / (1.0f + expf(-z.z));
    r.w = 1.0f / (1.0f + expf(-z.w));
    mp[i] = r;
}

// ---------- kernel 2: main fuzzy-AND + weighted partial sums ----------
__global__ __launch_bounds__(256, 4) void k_main(const float* __restrict__ x0,
                                                 const float* __restrict__ mu,
                                                 const float* __restrict__ rw,
                                                 float* __restrict__ partial) {
    const int lane  = threadIdx.x & 63;
    const int wave  = threadIdx.x >> 6;
    const int vslot = lane & 15;     // 16 v-slots of 16 v's each
    const int bloc  = lane >> 4;     // 4 batches per wave
    const int b     = blockIdx.x * BPB + wave * BPW + bloc;
    const int chunk = blockIdx.y;
    const int c0    = chunk * CCHUNK;

    // x-row slice register-resident: v = vslot*16 + i, i in [0,16)
    float xr[16];
    const float4* xp = reinterpret_cast<const float4*>(x0 + (size_t)b * V_ + vslot * 16);
#pragma unroll
    for (int i = 0; i < 4; ++i) {
        float4 v = xp[i];
        xr[4*i+0] = v.x; xr[4*i+1] = v.y; xr[4*i+2] = v.z; xr[4*i+3] = v.w;
    }

    const float* mb = mu + (size_t)c0 * TWOV + vslot * 16;

    // prefetch c0's mu slice (mu1: 4 float4, mu2: 4 float4)
    float4 A[4], Q[4];
    {
        const float4* m1 = reinterpret_cast<const float4*>(mb);
        const float4* m2 = reinterpret_cast<const float4*>(mb + V_);
#pragma unroll
        for (int i = 0; i < 4; ++i) { A[i] = m1[i]; Q[i] = m2[i]; }
    }

    float acc = 0.0f;
#pragma unroll
    for (int cc = 0; cc < CCHUNK; ++cc) {
        // software pipeline: issue next c's loads before computing current
        float4 An[4], Qn[4];
        if (cc + 1 < CCHUNK) {
            const float* nb = mb + (size_t)(cc + 1) * TWOV;
            const float4* n1 = reinterpret_cast<const float4*>(nb);
            const float4* n2 = reinterpret_cast<const float4*>(nb + V_);
#pragma unroll
            for (int i = 0; i < 4; ++i) { An[i] = n1[i]; Qn[i] = n2[i]; }
        }

        // 4 independent max chains; fmaxf(p, fmaxf(u,v)) fuses to v_max3_f32
        float p0 = 0.0f, p1 = 0.0f, p2 = 0.0f, p3 = 0.0f;
#pragma unroll
        for (int i = 0; i < 4; ++i) {
            p0 = fmaxf(p0, fmaxf(__builtin_fmaf(-A[i].x, xr[4*i+0], A[i].x), Q[i].x * xr[4*i+0]));
            p1 = fmaxf(p1, fmaxf(__builtin_fmaf(-A[i].y, xr[4*i+1], A[i].y), Q[i].y * xr[4*i+1]));
            p2 = fmaxf(p2, fmaxf(__builtin_fmaf(-A[i].z, xr[4*i+2], A[i].z), Q[i].z * xr[4*i+2]));
            p3 = fmaxf(p3, fmaxf(__builtin_fmaf(-A[i].w, xr[4*i+3], A[i].w), Q[i].w * xr[4*i+3]));
        }
        float m = fmaxf(fmaxf(p0, p1), fmaxf(p2, p3));
        // butterfly max across the 16 v-slots (lane bits 0..3)
        m = fmaxf(m, __shfl_xor(m, 1, 64));
        m = fmaxf(m, __shfl_xor(m, 2, 64));
        m = fmaxf(m, __shfl_xor(m, 4, 64));
        m = fmaxf(m, __shfl_xor(m, 8, 64));
        acc = __builtin_fmaf(rw[c0 + cc], 1.0f - m, acc);

        if (cc + 1 < CCHUNK) {
#pragma unroll
            for (int i = 0; i < 4; ++i) { A[i] = An[i]; Q[i] = Qn[i]; }
        }
    }
    if (vslot == 0) partial[(size_t)chunk * B_ + b] = acc;
}

// ---------- kernel 3: deterministic final reduction over c-chunks ----------
__global__ __launch_bounds__(256) void k_final(const float* __restrict__ partial,
                                               float* __restrict__ out) {
    int b = blockIdx.x * 256 + threadIdx.x;
    if (b < B_) {
        float s = 5.0f;
#pragma unroll
        for (int k = 0; k < NCHUNK; ++k) s += partial[(size_t)k * B_ + b];
        out[b] = s;
    }
}

// ---------- fallback (ws too small): naive but correct ----------
__global__ __launch_bounds__(256) void k_naive(const float* __restrict__ x0,
                                               const float* __restrict__ conj,
                                               const float* __restrict__ rw,
                                               float* __restrict__ out) {
    int b = blockIdx.x;
    int t = threadIdx.x;
    __shared__ float red[256];
    float acc = 0.0f;
    for (int c = t; c < C_; c += 256) {
        float m = 0.0f;
        for (int v = 0; v < V_; ++v) {
            float mu1 = 1.0f / (1.0f + expf(-conj[(size_t)c * TWOV + v]));
            float mu2 = 1.0f / (1.0f + expf(-conj[(size_t)c * TWOV + V_ + v]));
            float x = x0[(size_t)b * V_ + v];
            m = fmaxf(m, fmaxf(mu1 * (1.0f - x), mu2 * x));
        }
        acc += rw[c] * (1.0f - m);
    }
    red[t] = acc;
    __syncthreads();
    for (int s = 128; s > 0; s >>= 1) {
        if (t < s) red[t] += red[t + s];
        __syncthreads();
    }
    if (t == 0) out[b] = 5.0f + red[0];
}

extern "C" void kernel_launch(void* const* d_in, const int* in_sizes, int n_in,
                              void* d_out, int out_size, void* d_ws, size_t ws_size,
                              hipStream_t stream) {
    const float* x0   = (const float*)d_in[0];
    const float* conj = (const float*)d_in[1];
    const float* rw   = (const float*)d_in[2];
    float* out = (float*)d_out;

    const size_t mu_elems = (size_t)C_ * TWOV;            // 262144 floats
    const size_t part_elems = (size_t)NCHUNK * B_;        // 32768 floats
    const size_t need = (mu_elems + part_elems) * sizeof(float);

    if (ws_size < need) {
        k_naive<<<B_, 256, 0, stream>>>(x0, conj, rw, out);
        return;
    }

    float* mu = (float*)d_ws;
    float* partial = mu + mu_elems;

    k_sigmoid<<<(C_ * TWOV) / (256 * 4), 256, 0, stream>>>(conj, mu);
    dim3 grid(B_ / BPB, NCHUNK);  // 64 x 32 blocks; x-major = batch so
                                  // concurrent blocks share the same mu chunk in L2
    k_main<<<grid, 256, 0, stream>>>(x0, mu, rw, partial);
    k_final<<<(B_ + 255) / 256, 256, 0, stream>>>(partial, out);
}

// Round 3
// 37.438 us; speedup vs baseline: 3.4070x; 1.9031x over previous
//
#include <hip/hip_runtime.h>

// RuleNet: out[b] = 5 + sum_c rw[c] * min_j( mu[c,j]*x[b,j] + (1-mu[c,j]) )
// with x = [x0, 1-x0], mu = sigmoid(conjunctions).
// Rewrite: fit(b,c) = 1 - max_v max( mu1[c,v]*(1-x0[b,v]), mu2[c,v]*x0[b,v] )
//          mu1*(1-x) = fma(-mu1, x, mu1).
//
// Layout strategy: lane = conjunction (coalesced transposed-mu float2 loads),
// x0 wave-uniform broadcast loads, NO cross-lane ops in the inner loop.

#define B_    1024
#define C_    512
#define V_    256
#define TWOV  512

#define CPW    64              // conjunctions per wave (one per lane)
#define NCHUNK (C_ / CPW)      // 8 c-chunks
#define BPB    8               // batches per block
#define NBG    (B_ / BPB)      // 128 b-groups
#define WAVES  4               // waves per block, v-range split 4 x 64

// ---------- kernel 1: mu transpose+sigmoid: muT2[v][c] = (mu1, mu2) ----------
__global__ __launch_bounds__(256) void k_sigmoid_t(const float* __restrict__ conj,
                                                   float2* __restrict__ muT2) {
    const int c = blockIdx.x;        // 512 blocks
    const int v = threadIdx.x;       // 256 threads: full v range
    float z1 = conj[(size_t)c * TWOV + v];        // coalesced
    float z2 = conj[(size_t)c * TWOV + V_ + v];   // coalesced
    float m1 = 1.0f / (1.0f + expf(-z1));
    float m2 = 1.0f / (1.0f + expf(-z2));
    muT2[(size_t)v * C_ + c] = make_float2(m1, m2);  // scattered 8B, L2 absorbs
}

// ---------- kernel 2: main fuzzy-AND + weighted partial sums ----------
__global__ __launch_bounds__(256, 4) void k_main(const float* __restrict__ x0,
                                                 const float2* __restrict__ muT2,
                                                 const float* __restrict__ rw,
                                                 float* __restrict__ partial) {
    const int lane  = threadIdx.x & 63;
    const int wave  = threadIdx.x >> 6;          // v-range owner
    const int chunk = blockIdx.y;                // 8 chunks of 64 c
    const int c     = chunk * CPW + lane;        // this lane's conjunction
    const int bg    = blockIdx.x;                // 128 groups of 8 batches
    const int v0    = wave * 64;                 // this wave's v-range [v0, v0+64)

    const float* xb = x0 + (size_t)bg * BPB * V_;
    const float2* mup = muT2 + (size_t)v0 * C_ + c;

    float m[BPB];
#pragma unroll
    for (int i = 0; i < BPB; ++i) m[i] = 0.0f;

    for (int vv = 0; vv < 64; vv += 4) {
        // one coalesced float2 per v (mu1, mu2 for this lane's c)
        float2 u0 = mup[(size_t)(vv + 0) * C_];
        float2 u1 = mup[(size_t)(vv + 1) * C_];
        float2 u2 = mup[(size_t)(vv + 2) * C_];
        float2 u3 = mup[(size_t)(vv + 3) * C_];
#pragma unroll
        for (int bi = 0; bi < BPB; ++bi) {
            // wave-uniform broadcast load of 4 x-values
            float4 xv = *reinterpret_cast<const float4*>(xb + bi * V_ + v0 + vv);
            m[bi] = fmaxf(m[bi], fmaxf(__builtin_fmaf(-u0.x, xv.x, u0.x), u0.y * xv.x));
            m[bi] = fmaxf(m[bi], fmaxf(__builtin_fmaf(-u1.x, xv.y, u1.x), u1.y * xv.y));
            m[bi] = fmaxf(m[bi], fmaxf(__builtin_fmaf(-u2.x, xv.z, u2.x), u2.y * xv.z));
            m[bi] = fmaxf(m[bi], fmaxf(__builtin_fmaf(-u3.x, xv.w, u3.x), u3.y * xv.w));
        }
    }

    // cross-wave max combine (waves split the v-range); stride 9 avoids bank conflicts
    __shared__ float red[WAVES * 64 * 9];
#pragma unroll
    for (int bi = 0; bi < BPB; ++bi) red[(wave * 64 + lane) * 9 + bi] = m[bi];
    __syncthreads();

    if (wave == 0) {
        float w8[BPB];
        const float rwc = rw[c];
#pragma unroll
        for (int bi = 0; bi < BPB; ++bi) {
            float mm = red[(0 * 64 + lane) * 9 + bi];
            mm = fmaxf(mm, red[(1 * 64 + lane) * 9 + bi]);
            mm = fmaxf(mm, red[(2 * 64 + lane) * 9 + bi]);
            mm = fmaxf(mm, red[(3 * 64 + lane) * 9 + bi]);
            w8[bi] = rwc * (1.0f - mm);
        }
        // butterfly sum across 64 lanes (sum over this chunk's 64 conjunctions)
#pragma unroll
        for (int bi = 0; bi < BPB; ++bi) {
            float s = w8[bi];
            s += __shfl_xor(s, 1, 64);
            s += __shfl_xor(s, 2, 64);
            s += __shfl_xor(s, 4, 64);
            s += __shfl_xor(s, 8, 64);
            s += __shfl_xor(s, 16, 64);
            s += __shfl_xor(s, 32, 64);
            w8[bi] = s;
        }
        if (lane == 0) {
#pragma unroll
            for (int bi = 0; bi < BPB; ++bi)
                partial[(size_t)chunk * B_ + bg * BPB + bi] = w8[bi];
        }
    }
}

// ---------- kernel 3: deterministic final reduction over c-chunks ----------
__global__ __launch_bounds__(256) void k_final(const float* __restrict__ partial,
                                               float* __restrict__ out) {
    int b = blockIdx.x * 256 + threadIdx.x;
    if (b < B_) {
        float s = 5.0f;
#pragma unroll
        for (int k = 0; k < NCHUNK; ++k) s += partial[(size_t)k * B_ + b];
        out[b] = s;
    }
}

// ---------- fallback (ws too small): naive but correct ----------
__global__ __launch_bounds__(256) void k_naive(const float* __restrict__ x0,
                                               const float* __restrict__ conj,
                                               const float* __restrict__ rw,
                                               float* __restrict__ out) {
    int b = blockIdx.x;
    int t = threadIdx.x;
    __shared__ float red[256];
    float acc = 0.0f;
    for (int c = t; c < C_; c += 256) {
        float m = 0.0f;
        for (int v = 0; v < V_; ++v) {
            float mu1 = 1.0f / (1.0f + expf(-conj[(size_t)c * TWOV + v]));
            float mu2 = 1.0f / (1.0f + expf(-conj[(size_t)c * TWOV + V_ + v]));
            float x = x0[(size_t)b * V_ + v];
            m = fmaxf(m, fmaxf(mu1 * (1.0f - x), mu2 * x));
        }
        acc += rw[c] * (1.0f - m);
    }
    red[t] = acc;
    __syncthreads();
    for (int s = 128; s > 0; s >>= 1) {
        if (t < s) red[t] += red[t + s];
        __syncthreads();
    }
    if (t == 0) out[b] = 5.0f + red[0];
}

extern "C" void kernel_launch(void* const* d_in, const int* in_sizes, int n_in,
                              void* d_out, int out_size, void* d_ws, size_t ws_size,
                              hipStream_t stream) {
    const float* x0   = (const float*)d_in[0];
    const float* conj = (const float*)d_in[1];
    const float* rw   = (const float*)d_in[2];
    float* out = (float*)d_out;

    const size_t mu_elems = (size_t)C_ * TWOV;          // 262144 floats (1 MB as float2[V][C])
    const size_t part_elems = (size_t)NCHUNK * B_;      // 8192 floats
    const size_t need = (mu_elems + part_elems) * sizeof(float);

    if (ws_size < need) {
        k_naive<<<B_, 256, 0, stream>>>(x0, conj, rw, out);
        return;
    }

    float2* muT2 = (float2*)d_ws;
    float* partial = (float*)d_ws + mu_elems;

    k_sigmoid_t<<<C_, 256, 0, stream>>>(conj, muT2);
    dim3 grid(NBG, NCHUNK);   // 128 x 8 = 1024 blocks, 4 waves each
    k_main<<<grid, 256, 0, stream>>>(x0, muT2, rw, partial);
    k_final<<<(B_ + 255) / 256, 256, 0, stream>>>(partial, out);
}

// Round 4
// 32.967 us; speedup vs baseline: 3.8691x; 1.1356x over previous
//
#include <hip/hip_runtime.h>

// RuleNet: out[b] = 5 + sum_c rw[c] * min_j( mu[c,j]*x[b,j] + (1-mu[c,j]) )
// with x = [x0, 1-x0], mu = sigmoid(conjunctions).
// Rewrite: fit(b,c) = 1 - max_v max( mu1[c,v]*(1-x0[b,v]), mu2[c,v]*x0[b,v] )
//          mu1*(1-x) = fma(-mu1, x, mu1).
//
// Layout: lane = conjunction (coalesced transposed-mu float4 loads),
// x0 via SCALAR loads (readfirstlane-uniformed), no cross-lane in inner loop.
// 512-thread blocks, 8 waves/SIMD occupancy.

#define B_    1024
#define C_    512
#define V_    256
#define TWOV  512

#define CPW    64              // conjunctions per wave (one per lane)
#define NCHUNK (C_ / CPW)      // 8 c-chunks
#define BPB    8               // batches per block (== WAVES)
#define NBG    (B_ / BPB)      // 128 b-groups
#define WAVES  8               // waves per block, v-range split 8 x 32
#define VPW    (V_ / WAVES)    // 32 v per wave
#define NVP    (VPW / 2)       // 16 v-pairs per wave

// ---------- kernel 1: sigmoid + transpose, float4-packed ----------
// muT4[vp][c] = (mu1[2vp], mu2[2vp], mu1[2vp+1], mu2[2vp+1])
__global__ __launch_bounds__(512) void k_prep(const float* __restrict__ conj,
                                              float4* __restrict__ muT4) {
    const int vp = blockIdx.x;        // 128 v-pairs
    const int c  = threadIdx.x;       // 512 conjunctions
    const int v  = vp * 2;
    float z1a = conj[(size_t)c * TWOV + v];
    float z1b = conj[(size_t)c * TWOV + v + 1];
    float z2a = conj[(size_t)c * TWOV + V_ + v];
    float z2b = conj[(size_t)c * TWOV + V_ + v + 1];
    float4 r;
    r.x = 1.0f / (1.0f + __expf(-z1a));
    r.y = 1.0f / (1.0f + __expf(-z2a));
    r.z = 1.0f / (1.0f + __expf(-z1b));
    r.w = 1.0f / (1.0f + __expf(-z2b));
    muT4[(size_t)vp * C_ + c] = r;    // coalesced 16B x 512 lanes
}

// ---------- kernel 2: main fuzzy-AND + weighted partial sums ----------
__global__ __launch_bounds__(512, 8) void k_main(const float* __restrict__ x0,
                                                 const float4* __restrict__ muT4,
                                                 const float* __restrict__ rw,
                                                 float* __restrict__ partial) {
    const int lane   = threadIdx.x & 63;
    const int wave_u = __builtin_amdgcn_readfirstlane(threadIdx.x >> 6); // uniform!
    const int chunk  = blockIdx.y;               // 8 chunks of 64 c
    const int c      = chunk * CPW + lane;       // this lane's conjunction
    const int bg     = blockIdx.x;               // 128 groups of 8 batches
    const int vp0    = wave_u * NVP;             // this wave's v-pair range

    // uniform base -> compiler emits s_load for x (scalar pipe, free issue)
    const float*  xb  = x0 + (size_t)bg * BPB * V_ + wave_u * VPW;
    const float4* mup = muT4 + (size_t)vp0 * C_ + c;

    float m[BPB];
#pragma unroll
    for (int i = 0; i < BPB; ++i) m[i] = 0.0f;

#pragma unroll
    for (int p = 0; p < NVP; p += 2) {
        // coalesced per-lane mu: 4 v's worth in 2 dwordx4
        float4 ua = mup[(size_t)(p + 0) * C_];   // v = 2p, 2p+1
        float4 ub = mup[(size_t)(p + 1) * C_];   // v = 2p+2, 2p+3
#pragma unroll
        for (int bi = 0; bi < BPB; ++bi) {
            // wave-uniform scalar load of 4 x-values
            float4 xv = *reinterpret_cast<const float4*>(xb + bi * V_ + 2 * p);
            m[bi] = fmaxf(m[bi], fmaxf(__builtin_fmaf(-ua.x, xv.x, ua.x), ua.y * xv.x));
            m[bi] = fmaxf(m[bi], fmaxf(__builtin_fmaf(-ua.z, xv.y, ua.z), ua.w * xv.y));
            m[bi] = fmaxf(m[bi], fmaxf(__builtin_fmaf(-ub.x, xv.z, ub.x), ub.y * xv.z));
            m[bi] = fmaxf(m[bi], fmaxf(__builtin_fmaf(-ub.z, xv.w, ub.z), ub.w * xv.w));
        }
    }

    // cross-wave max combine: red[bi][wave][lane] -> conflict-free both directions
    __shared__ float red[BPB * WAVES * 64];
#pragma unroll
    for (int bi = 0; bi < BPB; ++bi)
        red[bi * (WAVES * 64) + threadIdx.x] = m[bi];
    __syncthreads();

    // wave w finishes batch bi = w (all 8 waves work in parallel)
    float mm = red[wave_u * (WAVES * 64) + lane];
#pragma unroll
    for (int k = 1; k < WAVES; ++k)
        mm = fmaxf(mm, red[wave_u * (WAVES * 64) + k * 64 + lane]);
    float s = rw[c] * (1.0f - mm);
    // butterfly sum across 64 lanes = sum over this chunk's 64 conjunctions
    s += __shfl_xor(s, 1, 64);
    s += __shfl_xor(s, 2, 64);
    s += __shfl_xor(s, 4, 64);
    s += __shfl_xor(s, 8, 64);
    s += __shfl_xor(s, 16, 64);
    s += __shfl_xor(s, 32, 64);
    if (lane == 0)
        partial[(size_t)chunk * B_ + bg * BPB + wave_u] = s;
}

// ---------- kernel 3: deterministic final reduction over c-chunks ----------
__global__ __launch_bounds__(256) void k_final(const float* __restrict__ partial,
                                               float* __restrict__ out) {
    int b = blockIdx.x * 256 + threadIdx.x;
    if (b < B_) {
        float s = 5.0f;
#pragma unroll
        for (int k = 0; k < NCHUNK; ++k) s += partial[(size_t)k * B_ + b];
        out[b] = s;
    }
}

// ---------- fallback (ws too small): naive but correct ----------
__global__ __launch_bounds__(256) void k_naive(const float* __restrict__ x0,
                                               const float* __restrict__ conj,
                                               const float* __restrict__ rw,
                                               float* __restrict__ out) {
    int b = blockIdx.x;
    int t = threadIdx.x;
    __shared__ float red[256];
    float acc = 0.0f;
    for (int c = t; c < C_; c += 256) {
        float m = 0.0f;
        for (int v = 0; v < V_; ++v) {
            float mu1 = 1.0f / (1.0f + expf(-conj[(size_t)c * TWOV + v]));
            float mu2 = 1.0f / (1.0f + expf(-conj[(size_t)c * TWOV + V_ + v]));
            float x = x0[(size_t)b * V_ + v];
            m = fmaxf(m, fmaxf(mu1 * (1.0f - x), mu2 * x));
        }
        acc += rw[c] * (1.0f - m);
    }
    red[t] = acc;
    __syncthreads();
    for (int s = 128; s > 0; s >>= 1) {
        if (t < s) red[t] += red[t + s];
        __syncthreads();
    }
    if (t == 0) out[b] = 5.0f + red[0];
}

extern "C" void kernel_launch(void* const* d_in, const int* in_sizes, int n_in,
                              void* d_out, int out_size, void* d_ws, size_t ws_size,
                              hipStream_t stream) {
    const float* x0   = (const float*)d_in[0];
    const float* conj = (const float*)d_in[1];
    const float* rw   = (const float*)d_in[2];
    float* out = (float*)d_out;

    const size_t mu_floats  = (size_t)(V_ / 2) * C_ * 4;   // 262144 floats (1 MB)
    const size_t part_elems = (size_t)NCHUNK * B_;         // 8192 floats
    const size_t need = (mu_floats + part_elems) * sizeof(float);

    if (ws_size < need) {
        k_naive<<<B_, 256, 0, stream>>>(x0, conj, rw, out);
        return;
    }

    float4* muT4   = (float4*)d_ws;
    float* partial = (float*)d_ws + mu_floats;

    k_prep<<<V_ / 2, 512, 0, stream>>>(conj, muT4);
    dim3 grid(NBG, NCHUNK);   // 128 x 8 = 1024 blocks; x-major = batch so
                              // concurrent blocks share the same mu chunk in L2
    k_main<<<grid, 512, 0, stream>>>(x0, muT4, rw, partial);
    k_final<<<(B_ + 255) / 256, 256, 0, stream>>>(partial, out);
}

// Round 5
// 32.058 us; speedup vs baseline: 3.9788x; 1.0284x over previous
//
#include <hip/hip_runtime.h>

// RuleNet: out[b] = 5 + sum_c rw[c] * min_j( mu[c,j]*x[b,j] + (1-mu[c,j]) )
// with x = [x0, 1-x0], mu = sigmoid(conjunctions).
// Rewrite: fit(b,c) = 1 - max_v max( mu1[c,v]*(1-x0[b,v]), mu2[c,v]*x0[b,v] )
//          mu1*(1-x) = fma(-mu1, x, mu1).
//
// Layout: lane = conjunction. mu slice register-resident (loaded once,
// coalesced float4). x via same-address vector loads (L1 broadcast) — NOT
// scalar/SMEM (R4 lesson: s_load chains serialize, 2% VALUBusy).

#define B_    1024
#define C_    512
#define V_    256
#define TWOV  512

#define CPW    64              // conjunctions per wave (one per lane)
#define NCHUNK (C_ / CPW)      // 8 c-chunks
#define BPB    8               // batches per block (== WAVES)
#define NBG    (B_ / BPB)      // 128 b-groups
#define WAVES  8               // waves per block, v-range split 8 x 32
#define VPW    32              // v per wave
#define HVP    8               // v-pairs per half (16 v per half, 2 halves)

// ---------- kernel 1: sigmoid + transpose ----------
// muT4[vp][c] = (mu1[2vp], mu2[2vp], mu1[2vp+1], mu2[2vp+1]), stored as float2 halves.
__global__ __launch_bounds__(256) void k_prep(const float* __restrict__ conj,
                                              float2* __restrict__ muT2) {
    const int c = blockIdx.x;        // 512 blocks
    const int v = threadIdx.x;       // 256 threads, coalesced loads
    float z1 = conj[(size_t)c * TWOV + v];
    float z2 = conj[(size_t)c * TWOV + V_ + v];
    float m1 = 1.0f / (1.0f + __expf(-z1));
    float m2 = 1.0f / (1.0f + __expf(-z2));
    // float2 element (v>>1)*1024 + c*2 + (v&1)  ==  muT4[v/2][c] half (v&1)
    muT2[(size_t)(v >> 1) * (2 * C_) + c * 2 + (v & 1)] = make_float2(m1, m2);
}

// ---------- kernel 2: main fuzzy-AND + weighted partial sums ----------
__global__ __launch_bounds__(512, 6) void k_main(const float* __restrict__ x0,
                                                 const float4* __restrict__ muT4,
                                                 const float* __restrict__ rw,
                                                 float* __restrict__ partial) {
    const int tid   = threadIdx.x;
    const int lane  = tid & 63;
    const int wave  = tid >> 6;                  // plain (vector loads for x!)
    const int chunk = blockIdx.y;                // 8 chunks of 64 c
    const int c     = chunk * CPW + lane;        // this lane's conjunction
    const int bg    = blockIdx.x;                // 128 groups of 8 batches
    const int v0    = wave * VPW;                // this wave's v-range

    const float*  xb  = x0 + (size_t)bg * BPB * V_ + v0;
    const float4* mup = muT4 + (size_t)(v0 >> 1) * C_ + c;

    float m[BPB];
#pragma unroll
    for (int i = 0; i < BPB; ++i) m[i] = 0.0f;

#pragma unroll
    for (int h = 0; h < 2; ++h) {
        // this half's mu slice: 8 float4 = 16 v, register-resident, loaded once
        float4 mr[HVP];
#pragma unroll
        for (int p = 0; p < HVP; ++p)
            mr[p] = mup[(size_t)(h * HVP + p) * C_];

#pragma unroll
        for (int bi = 0; bi < BPB; ++bi) {
            const float* xp = xb + bi * V_ + h * 16;
            // 4 broadcast float4 loads (all lanes same addr -> 1 L1 access each)
            float4 xa = *reinterpret_cast<const float4*>(xp);
            float4 xc = *reinterpret_cast<const float4*>(xp + 4);
            float4 xd = *reinterpret_cast<const float4*>(xp + 8);
            float4 xe = *reinterpret_cast<const float4*>(xp + 12);
            float mm = m[bi];
#define STEP(P, XA, XB) \
            mm = fmaxf(mm, fmaxf(__builtin_fmaf(-mr[P].x, (XA), mr[P].x), mr[P].y * (XA))); \
            mm = fmaxf(mm, fmaxf(__builtin_fmaf(-mr[P].z, (XB), mr[P].z), mr[P].w * (XB)));
            STEP(0, xa.x, xa.y)  STEP(1, xa.z, xa.w)
            STEP(2, xc.x, xc.y)  STEP(3, xc.z, xc.w)
            STEP(4, xd.x, xd.y)  STEP(5, xd.z, xd.w)
            STEP(6, xe.x, xe.y)  STEP(7, xe.z, xe.w)
#undef STEP
            m[bi] = mm;
        }
    }

    // cross-wave max combine: red[bi][tid] -> conflict-free both directions
    __shared__ float red[BPB * WAVES * 64];
#pragma unroll
    for (int bi = 0; bi < BPB; ++bi)
        red[bi * (WAVES * 64) + tid] = m[bi];
    __syncthreads();

    // wave w finishes batch bi = w (all 8 waves in parallel)
    float mm = red[wave * (WAVES * 64) + lane];
#pragma unroll
    for (int k = 1; k < WAVES; ++k)
        mm = fmaxf(mm, red[wave * (WAVES * 64) + k * 64 + lane]);
    float s = rw[c] * (1.0f - mm);
    // butterfly sum across 64 lanes = sum over this chunk's 64 conjunctions
    s += __shfl_xor(s, 1, 64);
    s += __shfl_xor(s, 2, 64);
    s += __shfl_xor(s, 4, 64);
    s += __shfl_xor(s, 8, 64);
    s += __shfl_xor(s, 16, 64);
    s += __shfl_xor(s, 32, 64);
    if (lane == 0)
        partial[(size_t)chunk * B_ + bg * BPB + wave] = s;
}

// ---------- kernel 3: deterministic final reduction over c-chunks ----------
__global__ __launch_bounds__(256) void k_final(const float* __restrict__ partial,
                                               float* __restrict__ out) {
    int b = blockIdx.x * 256 + threadIdx.x;
    if (b < B_) {
        float s = 5.0f;
#pragma unroll
        for (int k = 0; k < NCHUNK; ++k) s += partial[(size_t)k * B_ + b];
        out[b] = s;
    }
}

// ---------- fallback (ws too small): naive but correct ----------
__global__ __launch_bounds__(256) void k_naive(const float* __restrict__ x0,
                                               const float* __restrict__ conj,
                                               const float* __restrict__ rw,
                                               float* __restrict__ out) {
    int b = blockIdx.x;
    int t = threadIdx.x;
    __shared__ float red[256];
    float acc = 0.0f;
    for (int c = t; c < C_; c += 256) {
        float m = 0.0f;
        for (int v = 0; v < V_; ++v) {
            float mu1 = 1.0f / (1.0f + expf(-conj[(size_t)c * TWOV + v]));
            float mu2 = 1.0f / (1.0f + expf(-conj[(size_t)c * TWOV + V_ + v]));
            float x = x0[(size_t)b * V_ + v];
            m = fmaxf(m, fmaxf(mu1 * (1.0f - x), mu2 * x));
        }
        acc += rw[c] * (1.0f - m);
    }
    red[t] = acc;
    __syncthreads();
    for (int s = 128; s > 0; s >>= 1) {
        if (t < s) red[t] += red[t + s];
        __syncthreads();
    }
    if (t == 0) out[b] = 5.0f + red[0];
}

extern "C" void kernel_launch(void* const* d_in, const int* in_sizes, int n_in,
                              void* d_out, int out_size, void* d_ws, size_t ws_size,
                              hipStream_t stream) {
    const float* x0   = (const float*)d_in[0];
    const float* conj = (const float*)d_in[1];
    const float* rw   = (const float*)d_in[2];
    float* out = (float*)d_out;

    const size_t mu_floats  = (size_t)(V_ / 2) * C_ * 4;   // 262144 floats (1 MB)
    const size_t part_elems = (size_t)NCHUNK * B_;         // 8192 floats
    const size_t need = (mu_floats + part_elems) * sizeof(float);

    if (ws_size < need) {
        k_naive<<<B_, 256, 0, stream>>>(x0, conj, rw, out);
        return;
    }

    float4* muT4   = (float4*)d_ws;
    float* partial = (float*)d_ws + mu_floats;

    k_prep<<<C_, 256, 0, stream>>>(conj, (float2*)muT4);
    dim3 grid(NBG, NCHUNK);   // 128 x 8 = 1024 blocks; x-major = batch so
                              // concurrent blocks share the same mu chunk in L1/L2
    k_main<<<grid, 512, 0, stream>>>(x0, muT4, rw, partial);
    k_final<<<(B_ + 255) / 256, 256, 0, stream>>>(partial, out);
}

// Round 6
// 25.063 us; speedup vs baseline: 5.0894x; 1.2791x over previous
//
#include <hip/hip_runtime.h>

// RuleNet: out[b] = 5 + sum_c rw[c] * min_j( mu[c,j]*x[b,j] + (1-mu[c,j]) )
// with x = [x0, 1-x0], mu = sigmoid(conjunctions).
// Rewrite: fit(b,c) = 1 - max_v max( mu1[c,v]*(1-x0[b,v]), mu2[c,v]*x0[b,v] )
//          mu1*(1-x) = fma(-mu1, x, mu1).
//
// Layout: lane = conjunction. mu slice loaded ONCE per wave and PINNED in
// VGPRs via asm (R4/R5 lesson: compiler sinks "register-resident" loads back
// into the loop, re-streaming 16KB x8 through L1 -> 23% VALUBusy).
// x staged in LDS, read via wave-uniform ds_read (broadcast, zero L1 traffic).

#define B_    1024
#define C_    512
#define V_    256
#define TWOV  512

#define CPW    64              // conjunctions per wave (one per lane)
#define NCHUNK (C_ / CPW)      // 8 c-chunks
#define BPB    8               // batches per block (== WAVES)
#define NBG    (B_ / BPB)      // 128 b-groups
#define WAVES  8               // waves per block, v-range split 8 x 32
#define VPW    32              // v per wave
#define HVP    8               // float4 (v-pairs) per half: 16 v per half

// ---------- kernel 1: sigmoid + transpose ----------
// float2 element (v>>1)*1024 + c*2 + (v&1) = (mu1[v], mu2[v])
//  => float4 muT4[vp][c] = (mu1[2vp], mu2[2vp], mu1[2vp+1], mu2[2vp+1])
__global__ __launch_bounds__(256) void k_prep(const float* __restrict__ conj,
                                              float2* __restrict__ muT2) {
    const int c = blockIdx.x;        // 512 blocks
    const int v = threadIdx.x;       // 256 threads, coalesced loads
    float z1 = conj[(size_t)c * TWOV + v];
    float z2 = conj[(size_t)c * TWOV + V_ + v];
    float m1 = 1.0f / (1.0f + __expf(-z1));
    float m2 = 1.0f / (1.0f + __expf(-z2));
    muT2[(size_t)(v >> 1) * (2 * C_) + c * 2 + (v & 1)] = make_float2(m1, m2);
}

// ---------- kernel 2: main fuzzy-AND + weighted partial sums ----------
__global__ __launch_bounds__(512, 6) void k_main(const float* __restrict__ x0,
                                                 const float4* __restrict__ muT4,
                                                 const float* __restrict__ rw,
                                                 float* __restrict__ partial) {
    const int tid   = threadIdx.x;
    const int lane  = tid & 63;
    const int wave  = tid >> 6;
    const int chunk = blockIdx.y;                // 8 chunks of 64 c
    const int c     = chunk * CPW + lane;        // this lane's conjunction
    const int bg    = blockIdx.x;                // 128 groups of 8 batches
    const int v0    = wave * VPW;                // this wave's v-range

    __shared__ float4 xs[BPB * V_ / 4];          // 8 KB: x rows of this b-group
    __shared__ float  red[BPB * WAVES * 64];     // 16 KB: cross-wave max combine

    // stage x: 512 threads, one coalesced float4 each (8 rows x 1KB)
    {
        const float4* xg = reinterpret_cast<const float4*>(x0 + (size_t)bg * BPB * V_);
        xs[tid] = xg[tid];
    }

    const float4* mup = muT4 + (size_t)(v0 >> 1) * C_ + c;

    float m[BPB];
#pragma unroll
    for (int i = 0; i < BPB; ++i) m[i] = 0.0f;

    __syncthreads();

#pragma unroll
    for (int h = 0; h < 2; ++h) {
        // this half's mu slice: 8 float4 = 16 v, loaded once, PINNED in VGPRs
        float4 mr[HVP];
#pragma unroll
        for (int p = 0; p < HVP; ++p)
            mr[p] = mup[(size_t)(h * HVP + p) * C_];
#pragma unroll
        for (int p = 0; p < HVP; ++p)
            asm volatile("" : "+v"(mr[p].x), "+v"(mr[p].y), "+v"(mr[p].z), "+v"(mr[p].w));

#pragma unroll
        for (int bi = 0; bi < BPB; ++bi) {
            // wave-uniform LDS reads: same addr across lanes = free broadcast
            const int xb = bi * (V_ / 4) + (v0 >> 2) + h * 4;
            float4 xa = xs[xb + 0];
            float4 xc = xs[xb + 1];
            float4 xd = xs[xb + 2];
            float4 xe = xs[xb + 3];
            float mm = m[bi];
#define STEP(P, XA, XB) \
            mm = fmaxf(mm, fmaxf(__builtin_fmaf(-mr[P].x, (XA), mr[P].x), mr[P].y * (XA))); \
            mm = fmaxf(mm, fmaxf(__builtin_fmaf(-mr[P].z, (XB), mr[P].z), mr[P].w * (XB)));
            STEP(0, xa.x, xa.y)  STEP(1, xa.z, xa.w)
            STEP(2, xc.x, xc.y)  STEP(3, xc.z, xc.w)
            STEP(4, xd.x, xd.y)  STEP(5, xd.z, xd.w)
            STEP(6, xe.x, xe.y)  STEP(7, xe.z, xe.w)
#undef STEP
            m[bi] = mm;
        }
    }

    // cross-wave max combine: red[bi][tid] -> conflict-free both directions
#pragma unroll
    for (int bi = 0; bi < BPB; ++bi)
        red[bi * (WAVES * 64) + tid] = m[bi];
    __syncthreads();

    // wave w finishes batch bi = w (all 8 waves in parallel)
    float mm = red[wave * (WAVES * 64) + lane];
#pragma unroll
    for (int k = 1; k < WAVES; ++k)
        mm = fmaxf(mm, red[wave * (WAVES * 64) + k * 64 + lane]);
    float s = rw[c] * (1.0f - mm);
    // butterfly sum across 64 lanes = sum over this chunk's 64 conjunctions
    s += __shfl_xor(s, 1, 64);
    s += __shfl_xor(s, 2, 64);
    s += __shfl_xor(s, 4, 64);
    s += __shfl_xor(s, 8, 64);
    s += __shfl_xor(s, 16, 64);
    s += __shfl_xor(s, 32, 64);
    if (lane == 0)
        partial[(size_t)chunk * B_ + bg * BPB + wave] = s;
}

// ---------- kernel 3: deterministic final reduction over c-chunks ----------
__global__ __launch_bounds__(256) void k_final(const float* __restrict__ partial,
                                               float* __restrict__ out) {
    int b = blockIdx.x * 256 + threadIdx.x;
    if (b < B_) {
        float s = 5.0f;
#pragma unroll
        for (int k = 0; k < NCHUNK; ++k) s += partial[(size_t)k * B_ + b];
        out[b] = s;
    }
}

// ---------- fallback (ws too small): naive but correct ----------
__global__ __launch_bounds__(256) void k_naive(const float* __restrict__ x0,
                                               const float* __restrict__ conj,
                                               const float* __restrict__ rw,
                                               float* __restrict__ out) {
    int b = blockIdx.x;
    int t = threadIdx.x;
    __shared__ float red[256];
    float acc = 0.0f;
    for (int c = t; c < C_; c += 256) {
        float m = 0.0f;
        for (int v = 0; v < V_; ++v) {
            float mu1 = 1.0f / (1.0f + expf(-conj[(size_t)c * TWOV + v]));
            float mu2 = 1.0f / (1.0f + expf(-conj[(size_t)c * TWOV + V_ + v]));
            float x = x0[(size_t)b * V_ + v];
            m = fmaxf(m, fmaxf(mu1 * (1.0f - x), mu2 * x));
        }
        acc += rw[c] * (1.0f - m);
    }
    red[t] = acc;
    __syncthreads();
    for (int s = 128; s > 0; s >>= 1) {
        if (t < s) red[t] += red[t + s];
        __syncthreads();
    }
    if (t == 0) out[b] = 5.0f + red[0];
}

extern "C" void kernel_launch(void* const* d_in, const int* in_sizes, int n_in,
                              void* d_out, int out_size, void* d_ws, size_t ws_size,
                              hipStream_t stream) {
    const float* x0   = (const float*)d_in[0];
    const float* conj = (const float*)d_in[1];
    const float* rw   = (const float*)d_in[2];
    float* out = (float*)d_out;

    const size_t mu_floats  = (size_t)(V_ / 2) * C_ * 4;   // 262144 floats (1 MB)
    const size_t part_elems = (size_t)NCHUNK * B_;         // 8192 floats
    const size_t need = (mu_floats + part_elems) * sizeof(float);

    if (ws_size < need) {
        k_naive<<<B_, 256, 0, stream>>>(x0, conj, rw, out);
        return;
    }

    float4* muT4   = (float4*)d_ws;
    float* partial = (float*)d_ws + mu_floats;

    k_prep<<<C_, 256, 0, stream>>>(conj, (float2*)muT4);
    dim3 grid(NBG, NCHUNK);   // x-major = batch: consecutive blocks share the
                              // same mu chunk (L2 locality across XCD round-robin)
    k_main<<<grid, 512, 0, stream>>>(x0, muT4, rw, partial);
    k_final<<<(B_ + 255) / 256, 256, 0, stream>>>(partial, out);
}

// Round 7
// 25.062 us; speedup vs baseline: 5.0896x; 1.0000x over previous
//
#include <hip/hip_runtime.h>

// RuleNet: out[b] = 5 + sum_c rw[c] * min_j( mu[c,j]*x[b,j] + (1-mu[c,j]) )
// with x = [x0, 1-x0], mu = sigmoid(conjunctions).
// Rewrite: fit(b,c) = 1 - max_v max( mu1[c,v]*(1-x0[b,v]), mu2[c,v]*x0[b,v] )
//          mu1*(1-x) = fma(-mu1, x, mu1).
//
// Layout: each lane owns TWO conjunctions (c, c+64) -> every wave-uniform
// LDS x-read feeds 2x the VALU (R6 lesson: per-CU LDS pipe was ~2.5x
// oversubscribed vs VALU at 1 c/lane). mu slices pinned in VGPRs via asm
// (R5 lesson: compiler otherwise sinks the loads back into the loop).

#define B_    1024
#define C_    512
#define V_    256
#define TWOV  512

#define CPW    128             // conjunctions per wave (two per lane)
#define NCHUNK (C_ / CPW)      // 4 c-chunks
#define BPB    8               // batches per block (== WAVES)
#define NBG    (B_ / BPB)      // 128 b-groups
#define WAVES  8               // waves per block, v-range split 8 x 32
#define VPW    32              // v per wave
#define HVP    8               // float4 (v-pairs) per half: 16 v per half

// ---------- kernel 1: sigmoid + transpose ----------
// float2 element (v>>1)*1024 + c*2 + (v&1) = (mu1[v], mu2[v])
//  => float4 muT4[vp][c] = (mu1[2vp], mu2[2vp], mu1[2vp+1], mu2[2vp+1])
__global__ __launch_bounds__(256) void k_prep(const float* __restrict__ conj,
                                              float2* __restrict__ muT2) {
    const int c = blockIdx.x;        // 512 blocks
    const int v = threadIdx.x;       // 256 threads, coalesced loads
    float z1 = conj[(size_t)c * TWOV + v];
    float z2 = conj[(size_t)c * TWOV + V_ + v];
    float m1 = 1.0f / (1.0f + __expf(-z1));
    float m2 = 1.0f / (1.0f + __expf(-z2));
    muT2[(size_t)(v >> 1) * (2 * C_) + c * 2 + (v & 1)] = make_float2(m1, m2);
}

// ---------- kernel 2: main fuzzy-AND + weighted partial sums ----------
__global__ __launch_bounds__(512, 4) void k_main(const float* __restrict__ x0,
                                                 const float4* __restrict__ muT4,
                                                 const float* __restrict__ rw,
                                                 float* __restrict__ partial) {
    const int tid   = threadIdx.x;
    const int lane  = tid & 63;
    const int wave  = tid >> 6;
    const int chunk = blockIdx.y;                // 4 chunks of 128 c
    const int cA    = chunk * CPW + lane;        // lane's first conjunction
    const int cB    = cA + 64;                   // lane's second conjunction
    const int bg    = blockIdx.x;                // 128 groups of 8 batches
    const int v0    = wave * VPW;                // this wave's v-range

    __shared__ float4 xs[BPB * V_ / 4];          // 8 KB: x rows of this b-group
    __shared__ float  red[2 * BPB * WAVES * 64]; // 32 KB: cross-wave max combine

    // stage x: 512 threads, one coalesced float4 each (8 rows x 1KB)
    {
        const float4* xg = reinterpret_cast<const float4*>(x0 + (size_t)bg * BPB * V_);
        xs[tid] = xg[tid];
    }

    const float4* mup = muT4 + (size_t)(v0 >> 1) * C_ + cA;

    float mA[BPB], mB[BPB];
#pragma unroll
    for (int i = 0; i < BPB; ++i) { mA[i] = 0.0f; mB[i] = 0.0f; }

    __syncthreads();

#pragma unroll
    for (int h = 0; h < 2; ++h) {
        // this half's mu slices for both conjunctions: pinned in VGPRs
        float4 mrA[HVP], mrB[HVP];
#pragma unroll
        for (int p = 0; p < HVP; ++p) {
            mrA[p] = mup[(size_t)(h * HVP + p) * C_];
            mrB[p] = mup[(size_t)(h * HVP + p) * C_ + 64];
        }
#pragma unroll
        for (int p = 0; p < HVP; ++p) {
            asm volatile("" : "+v"(mrA[p].x), "+v"(mrA[p].y), "+v"(mrA[p].z), "+v"(mrA[p].w));
            asm volatile("" : "+v"(mrB[p].x), "+v"(mrB[p].y), "+v"(mrB[p].z), "+v"(mrB[p].w));
        }

#pragma unroll
        for (int bi = 0; bi < BPB; ++bi) {
            // wave-uniform LDS reads: same addr across lanes = free broadcast
            const int xb = bi * (V_ / 4) + (v0 >> 2) + h * 4;
            float4 xa = xs[xb + 0];
            float4 xc = xs[xb + 1];
            float4 xd = xs[xb + 2];
            float4 xe = xs[xb + 3];
            float ma = mA[bi], mb = mB[bi];
#define STEP(P, XA, XB) \
            ma = fmaxf(ma, fmaxf(__builtin_fmaf(-mrA[P].x, (XA), mrA[P].x), mrA[P].y * (XA))); \
            ma = fmaxf(ma, fmaxf(__builtin_fmaf(-mrA[P].z, (XB), mrA[P].z), mrA[P].w * (XB))); \
            mb = fmaxf(mb, fmaxf(__builtin_fmaf(-mrB[P].x, (XA), mrB[P].x), mrB[P].y * (XA))); \
            mb = fmaxf(mb, fmaxf(__builtin_fmaf(-mrB[P].z, (XB), mrB[P].z), mrB[P].w * (XB)));
            STEP(0, xa.x, xa.y)  STEP(1, xa.z, xa.w)
            STEP(2, xc.x, xc.y)  STEP(3, xc.z, xc.w)
            STEP(4, xd.x, xd.y)  STEP(5, xd.z, xd.w)
            STEP(6, xe.x, xe.y)  STEP(7, xe.z, xe.w)
#undef STEP
            mA[bi] = ma; mB[bi] = mb;
        }
    }

    // cross-wave max combine: red[cc][bi][wave][lane] (tid-consecutive writes)
#pragma unroll
    for (int bi = 0; bi < BPB; ++bi) {
        red[bi * (WAVES * 64) + tid] = mA[bi];
        red[(BPB + bi) * (WAVES * 64) + tid] = mB[bi];
    }
    __syncthreads();

    // wave w finishes batch bi = w (all 8 waves in parallel)
    float ma = red[wave * (WAVES * 64) + lane];
    float mb = red[(BPB + wave) * (WAVES * 64) + lane];
#pragma unroll
    for (int k = 1; k < WAVES; ++k) {
        ma = fmaxf(ma, red[wave * (WAVES * 64) + k * 64 + lane]);
        mb = fmaxf(mb, red[(BPB + wave) * (WAVES * 64) + k * 64 + lane]);
    }
    float s = rw[cA] * (1.0f - ma) + rw[cB] * (1.0f - mb);
    // butterfly sum across 64 lanes = sum over this chunk's 128 conjunctions
    s += __shfl_xor(s, 1, 64);
    s += __shfl_xor(s, 2, 64);
    s += __shfl_xor(s, 4, 64);
    s += __shfl_xor(s, 8, 64);
    s += __shfl_xor(s, 16, 64);
    s += __shfl_xor(s, 32, 64);
    if (lane == 0)
        partial[(size_t)chunk * B_ + bg * BPB + wave] = s;
}

// ---------- kernel 3: deterministic final reduction over c-chunks ----------
__global__ __launch_bounds__(256) void k_final(const float* __restrict__ partial,
                                               float* __restrict__ out) {
    int b = blockIdx.x * 256 + threadIdx.x;
    if (b < B_) {
        float s = 5.0f;
#pragma unroll
        for (int k = 0; k < NCHUNK; ++k) s += partial[(size_t)k * B_ + b];
        out[b] = s;
    }
}

// ---------- fallback (ws too small): naive but correct ----------
__global__ __launch_bounds__(256) void k_naive(const float* __restrict__ x0,
                                               const float* __restrict__ conj,
                                               const float* __restrict__ rw,
                                               float* __restrict__ out) {
    int b = blockIdx.x;
    int t = threadIdx.x;
    __shared__ float red[256];
    float acc = 0.0f;
    for (int c = t; c < C_; c += 256) {
        float m = 0.0f;
        for (int v = 0; v < V_; ++v) {
            float mu1 = 1.0f / (1.0f + expf(-conj[(size_t)c * TWOV + v]));
            float mu2 = 1.0f / (1.0f + expf(-conj[(size_t)c * TWOV + V_ + v]));
            float x = x0[(size_t)b * V_ + v];
            m = fmaxf(m, fmaxf(mu1 * (1.0f - x), mu2 * x));
        }
        acc += rw[c] * (1.0f - m);
    }
    red[t] = acc;
    __syncthreads();
    for (int s = 128; s > 0; s >>= 1) {
        if (t < s) red[t] += red[t + s];
        __syncthreads();
    }
    if (t == 0) out[b] = 5.0f + red[0];
}

extern "C" void kernel_launch(void* const* d_in, const int* in_sizes, int n_in,
                              void* d_out, int out_size, void* d_ws, size_t ws_size,
                              hipStream_t stream) {
    const float* x0   = (const float*)d_in[0];
    const float* conj = (const float*)d_in[1];
    const float* rw   = (const float*)d_in[2];
    float* out = (float*)d_out;

    const size_t mu_floats  = (size_t)(V_ / 2) * C_ * 4;   // 262144 floats (1 MB)
    const size_t part_elems = (size_t)NCHUNK * B_;         // 4096 floats
    const size_t need = (mu_floats + part_elems) * sizeof(float);

    if (ws_size < need) {
        k_naive<<<B_, 256, 0, stream>>>(x0, conj, rw, out);
        return;
    }

    float4* muT4   = (float4*)d_ws;
    float* partial = (float*)d_ws + mu_floats;

    k_prep<<<C_, 256, 0, stream>>>(conj, (float2*)muT4);
    dim3 grid(NBG, NCHUNK);   // 128 x 4 = 512 blocks; x-major = batch so
                              // concurrent blocks share the same mu chunk in L2
    k_main<<<grid, 512, 0, stream>>>(x0, muT4, rw, partial);
    k_final<<<(B_ + 255) / 256, 256, 0, stream>>>(partial, out);
}

// Round 8
// 23.830 us; speedup vs baseline: 5.3526x; 1.0517x over previous
//
#include <hip/hip_runtime.h>

// RuleNet: out[b] = 5 + sum_c rw[c] * min_j( mu[c,j]*x[b,j] + (1-mu[c,j]) )
// with x = [x0, 1-x0], mu = sigmoid(conjunctions).
// Rewrite: fit(b,c) = 1 - max_v max( mu1[c,v]*(1-x0[b,v]), mu2[c,v]*x0[b,v] )
//          mu1*(1-x) = fma(-mu1, x, mu1).
//
// R8: fuse k_final into k_main via atomicAdd (out pre-initialized to 5.0 by
// k_prep). Hot loop identical to R7 (pinned-VGPR mu, LDS x broadcast).
// Tests the "3-kernel pipeline overhead" hypothesis in isolation.

#define B_    1024
#define C_    512
#define V_    256
#define TWOV  512

#define CPW    128             // conjunctions per wave (two per lane)
#define NCHUNK (C_ / CPW)      // 4 c-chunks
#define BPB    8               // batches per block (== WAVES)
#define NBG    (B_ / BPB)      // 128 b-groups
#define WAVES  8               // waves per block, v-range split 8 x 32
#define VPW    32              // v per wave
#define HVP    8               // float4 (v-pairs) per half: 16 v per half

// ---------- kernel 1: sigmoid + transpose, plus out[b]=5.0 init ----------
// float2 element (v>>1)*1024 + c*2 + (v&1) = (mu1[v], mu2[v])
//  => float4 muT4[vp][c] = (mu1[2vp], mu2[2vp], mu1[2vp+1], mu2[2vp+1])
__global__ __launch_bounds__(256) void k_prep(const float* __restrict__ conj,
                                              float2* __restrict__ muT2,
                                              float* __restrict__ out) {
    const int c = blockIdx.x;        // 512 blocks
    const int v = threadIdx.x;       // 256 threads, coalesced loads
    if (c < 4) out[c * 256 + v] = 5.0f;   // init accumulator target
    float z1 = conj[(size_t)c * TWOV + v];
    float z2 = conj[(size_t)c * TWOV + V_ + v];
    float m1 = 1.0f / (1.0f + __expf(-z1));
    float m2 = 1.0f / (1.0f + __expf(-z2));
    muT2[(size_t)(v >> 1) * (2 * C_) + c * 2 + (v & 1)] = make_float2(m1, m2);
}

// ---------- kernel 2: main fuzzy-AND + fused weighted-sum epilogue ----------
__global__ __launch_bounds__(512, 4) void k_main(const float* __restrict__ x0,
                                                 const float4* __restrict__ muT4,
                                                 const float* __restrict__ rw,
                                                 float* __restrict__ out) {
    const int tid   = threadIdx.x;
    const int lane  = tid & 63;
    const int wave  = tid >> 6;
    const int chunk = blockIdx.y;                // 4 chunks of 128 c
    const int cA    = chunk * CPW + lane;        // lane's first conjunction
    const int cB    = cA + 64;                   // lane's second conjunction
    const int bg    = blockIdx.x;                // 128 groups of 8 batches
    const int v0    = wave * VPW;                // this wave's v-range

    __shared__ float4 xs[BPB * V_ / 4];          // 8 KB: x rows of this b-group
    __shared__ float  red[2 * BPB * WAVES * 64]; // 32 KB: cross-wave max combine

    // stage x: 512 threads, one coalesced float4 each (8 rows x 1KB)
    {
        const float4* xg = reinterpret_cast<const float4*>(x0 + (size_t)bg * BPB * V_);
        xs[tid] = xg[tid];
    }

    const float4* mup = muT4 + (size_t)(v0 >> 1) * C_ + cA;

    float mA[BPB], mB[BPB];
#pragma unroll
    for (int i = 0; i < BPB; ++i) { mA[i] = 0.0f; mB[i] = 0.0f; }

    __syncthreads();

#pragma unroll
    for (int h = 0; h < 2; ++h) {
        // this half's mu slices for both conjunctions: pinned in VGPRs
        float4 mrA[HVP], mrB[HVP];
#pragma unroll
        for (int p = 0; p < HVP; ++p) {
            mrA[p] = mup[(size_t)(h * HVP + p) * C_];
            mrB[p] = mup[(size_t)(h * HVP + p) * C_ + 64];
        }
#pragma unroll
        for (int p = 0; p < HVP; ++p) {
            asm volatile("" : "+v"(mrA[p].x), "+v"(mrA[p].y), "+v"(mrA[p].z), "+v"(mrA[p].w));
            asm volatile("" : "+v"(mrB[p].x), "+v"(mrB[p].y), "+v"(mrB[p].z), "+v"(mrB[p].w));
        }

#pragma unroll
        for (int bi = 0; bi < BPB; ++bi) {
            // wave-uniform LDS reads: same addr across lanes = free broadcast
            const int xb = bi * (V_ / 4) + (v0 >> 2) + h * 4;
            float4 xa = xs[xb + 0];
            float4 xc = xs[xb + 1];
            float4 xd = xs[xb + 2];
            float4 xe = xs[xb + 3];
            float ma = mA[bi], mb = mB[bi];
#define STEP(P, XA, XB) \
            ma = fmaxf(ma, fmaxf(__builtin_fmaf(-mrA[P].x, (XA), mrA[P].x), mrA[P].y * (XA))); \
            ma = fmaxf(ma, fmaxf(__builtin_fmaf(-mrA[P].z, (XB), mrA[P].z), mrA[P].w * (XB))); \
            mb = fmaxf(mb, fmaxf(__builtin_fmaf(-mrB[P].x, (XA), mrB[P].x), mrB[P].y * (XA))); \
            mb = fmaxf(mb, fmaxf(__builtin_fmaf(-mrB[P].z, (XB), mrB[P].z), mrB[P].w * (XB)));
            STEP(0, xa.x, xa.y)  STEP(1, xa.z, xa.w)
            STEP(2, xc.x, xc.y)  STEP(3, xc.z, xc.w)
            STEP(4, xd.x, xd.y)  STEP(5, xd.z, xd.w)
            STEP(6, xe.x, xe.y)  STEP(7, xe.z, xe.w)
#undef STEP
            mA[bi] = ma; mB[bi] = mb;
        }
    }

    // cross-wave max combine: red[cc][bi][wave][lane] (tid-consecutive writes)
#pragma unroll
    for (int bi = 0; bi < BPB; ++bi) {
        red[bi * (WAVES * 64) + tid] = mA[bi];
        red[(BPB + bi) * (WAVES * 64) + tid] = mB[bi];
    }
    __syncthreads();

    // wave w finishes batch bi = w (all 8 waves in parallel)
    float ma = red[wave * (WAVES * 64) + lane];
    float mb = red[(BPB + wave) * (WAVES * 64) + lane];
#pragma unroll
    for (int k = 1; k < WAVES; ++k) {
        ma = fmaxf(ma, red[wave * (WAVES * 64) + k * 64 + lane]);
        mb = fmaxf(mb, red[(BPB + wave) * (WAVES * 64) + k * 64 + lane]);
    }
    float s = rw[cA] * (1.0f - ma) + rw[cB] * (1.0f - mb);
    // butterfly sum across 64 lanes = sum over this chunk's 128 conjunctions
    s += __shfl_xor(s, 1, 64);
    s += __shfl_xor(s, 2, 64);
    s += __shfl_xor(s, 4, 64);
    s += __shfl_xor(s, 8, 64);
    s += __shfl_xor(s, 16, 64);
    s += __shfl_xor(s, 32, 64);
    if (lane == 0)
        atomicAdd(&out[bg * BPB + wave], s);   // 4 adds per element (one per chunk)
}

// ---------- fallback (ws too small): naive but correct ----------
__global__ __launch_bounds__(256) void k_naive(const float* __restrict__ x0,
                                               const float* __restrict__ conj,
                                               const float* __restrict__ rw,
                                               float* __restrict__ out) {
    int b = blockIdx.x;
    int t = threadIdx.x;
    __shared__ float red[256];
    float acc = 0.0f;
    for (int c = t; c < C_; c += 256) {
        float m = 0.0f;
        for (int v = 0; v < V_; ++v) {
            float mu1 = 1.0f / (1.0f + expf(-conj[(size_t)c * TWOV + v]));
            float mu2 = 1.0f / (1.0f + expf(-conj[(size_t)c * TWOV + V_ + v]));
            float x = x0[(size_t)b * V_ + v];
            m = fmaxf(m, fmaxf(mu1 * (1.0f - x), mu2 * x));
        }
        acc += rw[c] * (1.0f - m);
    }
    red[t] = acc;
    __syncthreads();
    for (int s = 128; s > 0; s >>= 1) {
        if (t < s) red[t] += red[t + s];
        __syncthreads();
    }
    if (t == 0) out[b] = 5.0f + red[0];
}

extern "C" void kernel_launch(void* const* d_in, const int* in_sizes, int n_in,
                              void* d_out, int out_size, void* d_ws, size_t ws_size,
                              hipStream_t stream) {
    const float* x0   = (const float*)d_in[0];
    const float* conj = (const float*)d_in[1];
    const float* rw   = (const float*)d_in[2];
    float* out = (float*)d_out;

    const size_t mu_floats = (size_t)(V_ / 2) * C_ * 4;   // 262144 floats (1 MB)
    const size_t need = mu_floats * sizeof(float);

    if (ws_size < need) {
        k_naive<<<B_, 256, 0, stream>>>(x0, conj, rw, out);
        return;
    }

    float4* muT4 = (float4*)d_ws;

    k_prep<<<C_, 256, 0, stream>>>(conj, (float2*)muT4, out);
    dim3 grid(NBG, NCHUNK);   // 128 x 4 = 512 blocks; x-major = batch so
                              // concurrent blocks share the same mu chunk in L2
    k_main<<<grid, 512, 0, stream>>>(x0, muT4, rw, out);
}